// Round 2
// baseline (59.738 us; speedup 1.0000x reference)
//
#include <hip/hip_runtime.h>

#define NUM_CODE 2048
#define DIM_CODE 512

// One block (256 threads = 4 waves) per row.
// All four 16B global loads (x lo/hi, noise lo/hi) are issued up front so
// the wave has a single merged memory phase; the softmax reductions then
// overlap the in-flight noise loads.
__global__ __launch_bounds__(256) void vq_row_kernel(
    const float* __restrict__ x,
    const float* __restrict__ noise,
    const float* __restrict__ codebook,
    float* __restrict__ out)
{
    __shared__ float s_f[4];
    __shared__ float s_bv[4];
    __shared__ int   s_bi[4];

    const int row  = blockIdx.x;
    const int tid  = threadIdx.x;
    const int lane = tid & 63;
    const int wave = tid >> 6;

    const float4* x4 = (const float4*)(x     + (size_t)row * NUM_CODE);
    const float4* n4 = (const float4*)(noise + (size_t)row * NUM_CODE);

    // ---- issue ALL global loads up front (4 x 16B per lane in flight) ----
    const float4 a  = x4[tid];        // x elements 4*tid .. 4*tid+3
    const float4 b  = x4[256 + tid];  // x elements 1024+4*tid .. +3
    const float4 na = n4[tid];        // noise, same mapping
    const float4 nb = n4[256 + tid];

    // ---- row max ----
    float m = fmaxf(fmaxf(fmaxf(a.x, a.y), fmaxf(a.z, a.w)),
                    fmaxf(fmaxf(b.x, b.y), fmaxf(b.z, b.w)));
    #pragma unroll
    for (int off = 32; off; off >>= 1)
        m = fmaxf(m, __shfl_xor(m, off));
    if (lane == 0) s_f[wave] = m;
    __syncthreads();
    m = fmaxf(fmaxf(s_f[0], s_f[1]), fmaxf(s_f[2], s_f[3]));
    __syncthreads();  // s_f reused below

    // ---- exp + row sum (same order as the passing R0 kernel) ----
    float e0 = expf(a.x - m), e1 = expf(a.y - m), e2 = expf(a.z - m), e3 = expf(a.w - m);
    float e4 = expf(b.x - m), e5 = expf(b.y - m), e6 = expf(b.z - m), e7 = expf(b.w - m);
    float s = ((e0 + e1) + (e2 + e3)) + ((e4 + e5) + (e6 + e7));
    #pragma unroll
    for (int off = 32; off; off >>= 1)
        s += __shfl_xor(s, off);
    if (lane == 0) s_f[wave] = s;
    __syncthreads();
    s = (s_f[0] + s_f[1]) + (s_f[2] + s_f[3]);

    // ---- argmax(sm - noise), first-index tie-break ----
    const int i0 = 4 * tid;          // a.x..a.w -> i0..i0+3
    const int i1 = 1024 + 4 * tid;   // b.x..b.w -> i1..i1+3

    float bv = e0 / s - na.x; int bi = i0;
    { float v = e1 / s - na.y; if (v > bv) { bv = v; bi = i0 + 1; } }
    { float v = e2 / s - na.z; if (v > bv) { bv = v; bi = i0 + 2; } }
    { float v = e3 / s - na.w; if (v > bv) { bv = v; bi = i0 + 3; } }
    { float v = e4 / s - nb.x; if (v > bv) { bv = v; bi = i1;     } }
    { float v = e5 / s - nb.y; if (v > bv) { bv = v; bi = i1 + 1; } }
    { float v = e6 / s - nb.z; if (v > bv) { bv = v; bi = i1 + 2; } }
    { float v = e7 / s - nb.w; if (v > bv) { bv = v; bi = i1 + 3; } }

    #pragma unroll
    for (int off = 32; off; off >>= 1) {
        float ov = __shfl_xor(bv, off);
        int   oi = __shfl_xor(bi, off);
        if (ov > bv || (ov == bv && oi < bi)) { bv = ov; bi = oi; }
    }
    if (lane == 0) { s_bv[wave] = bv; s_bi[wave] = bi; }
    __syncthreads();
    bv = s_bv[0]; bi = s_bi[0];
    #pragma unroll
    for (int w = 1; w < 4; ++w) {
        float ov = s_bv[w]; int oi = s_bi[w];
        if (ov > bv || (ov == bv && oi < bi)) { bv = ov; bi = oi; }
    }

    // ---- gather codebook[bi] -> out[row], float4 via first 128 threads ----
    if (tid < 128) {
        const float4* cb = (const float4*)(codebook + (size_t)bi * DIM_CODE);
        float4*       o  = (float4*)(out + (size_t)row * DIM_CODE);
        o[tid] = cb[tid];  // 128 threads x 16B = 2 KB row
    }
}

extern "C" void kernel_launch(void* const* d_in, const int* in_sizes, int n_in,
                              void* d_out, int out_size, void* d_ws, size_t ws_size,
                              hipStream_t stream) {
    const float* x        = (const float*)d_in[0];
    const float* noise    = (const float*)d_in[1];
    const float* codebook = (const float*)d_in[2];
    float* out            = (float*)d_out;

    const int n_rows = in_sizes[0] / NUM_CODE;  // 16384

    vq_row_kernel<<<n_rows, 256, 0, stream>>>(x, noise, codebook, out);
}

// Round 3
// 55.925 us; speedup vs baseline: 1.0682x; 1.0682x over previous
//
#include <hip/hip_runtime.h>

#define NUM_CODE 2048
#define DIM_CODE 512

// One block (256 threads = 4 waves) per row. R0 structure + single
// reciprocal instead of 8 IEEE divisions (VALU was the binding pipe).
__global__ __launch_bounds__(256) void vq_row_kernel(
    const float* __restrict__ x,
    const float* __restrict__ noise,
    const float* __restrict__ codebook,
    float* __restrict__ out)
{
    __shared__ float s_f[4];
    __shared__ float s_bv[4];
    __shared__ int   s_bi[4];

    const int row  = blockIdx.x;
    const int tid  = threadIdx.x;
    const int lane = tid & 63;
    const int wave = tid >> 6;

    const float4* x4 = (const float4*)(x     + (size_t)row * NUM_CODE);
    const float4* n4 = (const float4*)(noise + (size_t)row * NUM_CODE);

    const float4 a = x4[tid];        // elements 4*tid .. 4*tid+3
    const float4 b = x4[256 + tid];  // elements 1024+4*tid .. +3

    // ---- row max ----
    float m = fmaxf(fmaxf(fmaxf(a.x, a.y), fmaxf(a.z, a.w)),
                    fmaxf(fmaxf(b.x, b.y), fmaxf(b.z, b.w)));
    #pragma unroll
    for (int off = 32; off; off >>= 1)
        m = fmaxf(m, __shfl_xor(m, off));
    if (lane == 0) s_f[wave] = m;
    __syncthreads();
    m = fmaxf(fmaxf(s_f[0], s_f[1]), fmaxf(s_f[2], s_f[3]));
    __syncthreads();  // s_f reused below

    // ---- exp + row sum ----
    float e0 = expf(a.x - m), e1 = expf(a.y - m), e2 = expf(a.z - m), e3 = expf(a.w - m);
    float e4 = expf(b.x - m), e5 = expf(b.y - m), e6 = expf(b.z - m), e7 = expf(b.w - m);
    float s = ((e0 + e1) + (e2 + e3)) + ((e4 + e5) + (e6 + e7));
    #pragma unroll
    for (int off = 32; off; off >>= 1)
        s += __shfl_xor(s, off);
    if (lane == 0) s_f[wave] = s;
    __syncthreads();
    s = (s_f[0] + s_f[1]) + (s_f[2] + s_f[3]);

    // one division per thread; argmax values use e_i * inv (<=1 ulp extra
    // perturbation on sm ~ same class as f64-vs-f32, which flipped nothing)
    const float inv = 1.0f / s;

    // ---- argmax(sm - noise), first-index tie-break ----
    const float4 na = n4[tid];
    const float4 nb = n4[256 + tid];

    const int i0 = 4 * tid;          // a.x..a.w -> i0..i0+3
    const int i1 = 1024 + 4 * tid;   // b.x..b.w -> i1..i1+3

    float bv = e0 * inv - na.x; int bi = i0;
    { float v = e1 * inv - na.y; if (v > bv) { bv = v; bi = i0 + 1; } }
    { float v = e2 * inv - na.z; if (v > bv) { bv = v; bi = i0 + 2; } }
    { float v = e3 * inv - na.w; if (v > bv) { bv = v; bi = i0 + 3; } }
    { float v = e4 * inv - nb.x; if (v > bv) { bv = v; bi = i1;     } }
    { float v = e5 * inv - nb.y; if (v > bv) { bv = v; bi = i1 + 1; } }
    { float v = e6 * inv - nb.z; if (v > bv) { bv = v; bi = i1 + 2; } }
    { float v = e7 * inv - nb.w; if (v > bv) { bv = v; bi = i1 + 3; } }

    #pragma unroll
    for (int off = 32; off; off >>= 1) {
        float ov = __shfl_xor(bv, off);
        int   oi = __shfl_xor(bi, off);
        if (ov > bv || (ov == bv && oi < bi)) { bv = ov; bi = oi; }
    }
    if (lane == 0) { s_bv[wave] = bv; s_bi[wave] = bi; }
    __syncthreads();
    bv = s_bv[0]; bi = s_bi[0];
    #pragma unroll
    for (int w = 1; w < 4; ++w) {
        float ov = s_bv[w]; int oi = s_bi[w];
        if (ov > bv || (ov == bv && oi < bi)) { bv = ov; bi = oi; }
    }

    // ---- gather codebook[bi] -> out[row] ----
    const float2* cb = (const float2*)(codebook + (size_t)bi * DIM_CODE);
    float2*       o  = (float2*)(out + (size_t)row * DIM_CODE);
    o[tid] = cb[tid];  // 256 threads x 8B = 2 KB row
}

extern "C" void kernel_launch(void* const* d_in, const int* in_sizes, int n_in,
                              void* d_out, int out_size, void* d_ws, size_t ws_size,
                              hipStream_t stream) {
    const float* x        = (const float*)d_in[0];
    const float* noise    = (const float*)d_in[1];
    const float* codebook = (const float*)d_in[2];
    float* out            = (float*)d_out;

    const int n_rows = in_sizes[0] / NUM_CODE;  // 16384

    vq_row_kernel<<<n_rows, 256, 0, stream>>>(x, noise, codebook, out);
}